// Round 8
// baseline (388.670 us; speedup 1.0000x reference)
//
#include <hip/hip_runtime.h>
#include <math.h>

#define NF 8
#define SS 5
#define DIN 64
#define KSTEP 3
#define BT 32
#define FH_PAD 68              // padded row (16B-aligned, bank spread)
#define FSTR (SS*FH_PAD)       // 340 (%32 = 20 -> 8 distinct start banks)
#define FH0_SZ (NF*FSTR)       // 2720 floats: hop-0 fh, padded
#define NSQ_OFF FH0_SZ         // ws: nsqh [3][8][5]
#define AH_OFF  (FH0_SZ + KSTEP*NF*SS)   // ws: Ah [8][5][5]

// exp(-(sqf+sqh-2cr)/3.2) = 2^(CC*cr - CS*sqf - CS*sqh)
#define CS 0.45084219902780109f
#define CC 0.90168439805560218f

__device__ __forceinline__ float fexp2(float x) {
#if __has_builtin(__builtin_amdgcn_exp2f)
  return __builtin_amdgcn_exp2f(x);
#else
  return exp2f(x);
#endif
}

// symmetric 5x5 index (i<=j): base i*(9-i)/2 + j ; folds at compile time
__device__ __forceinline__ constexpr int midx(int i, int j) {
  return (i <= j) ? (i*(9-i))/2 + j : (j*(9-j))/2 + i;
}

// e in [0,15) -> (i,j) upper-triangle entry
__device__ __forceinline__ void tri_ij(int e, int& i, int& j) {
  int i_ = (e >= 5) + (e >= 9) + (e >= 12) + (e >= 14);
  int off = (i_ == 0) ? 0 : (i_ == 1) ? 4 : (i_ == 2) ? 7 : (i_ == 3) ? 9 : 10;
  i = i_; j = e - off;
}

__global__ __launch_bounds__(256) void hidden_prep(
    const float* __restrict__ adjs_hidden,
    const float* __restrict__ features_hidden,
    float* __restrict__ ws)
{
  __shared__ float Ah[NF][SS][SS];
  __shared__ float buf[2][NF][SS][DIN];
  const int t = threadIdx.x;

  if (t < NF*SS*SS) ((float*)Ah)[t] = 0.0f;
  for (int i = t; i < NF*SS*DIN; i += 256) ((float*)buf[0])[i] = features_hidden[i];
  __syncthreads();
  if (t < NF*10) {
    const int iu0[10] = {0,0,0,0,1,1,1,2,2,3};
    const int iu1[10] = {1,2,3,4,2,3,4,3,4,4};
    int f = t / 10, k = t % 10;
    float sg = 1.0f / (1.0f + expf(-adjs_hidden[t]));
    Ah[f][iu0[k]][iu1[k]] = sg;
    Ah[f][iu1[k]][iu0[k]] = sg;
  }
  __syncthreads();

  // export Ah for the main kernel
  if (t < NF*SS*SS) ws[AH_OFF + t] = ((float*)Ah)[t];

  int cur = 0;
  for (int h = 0; h < KSTEP; ++h) {
    // hop-0 fh only (padded layout for LDS staging)
    if (h == 0) {
      for (int i = t; i < NF*SS*DIN; i += 256) {
        int f = i / (SS*DIN), s = (i / DIN) % SS, d = i % DIN;
        ws[f*FSTR + s*FH_PAD + d] = buf[cur][f][s][d];
      }
    }
    // negated, pre-scaled sq_h (all hops)
    if (t < NF*SS) {
      float acc = 0.0f;
      int f = t / SS, s = t % SS;
      for (int d = 0; d < DIN; ++d) { float v = buf[cur][f][s][d]; acc = fmaf(v, v, acc); }
      ws[NSQ_OFF + h*NF*SS + t] = -acc * CS;
    }
    if (h + 1 < KSTEP) {
      __syncthreads();
      for (int i = t; i < NF*SS*DIN; i += 256) {
        int f = i / (SS*DIN), s = (i / DIN) % SS, d = i % DIN;
        float acc = 0.0f;
        for (int j = 0; j < SS; ++j) acc = fmaf(Ah[f][s][j], buf[cur][f][j][d], acc);
        buf[cur^1][f][s][d] = acc;
      }
      __syncthreads();
      cur ^= 1;
    }
  }
}

// Linearity restructure: the d=64 contraction runs ONCE (hop 0) producing
// G = f.fh^T (5x5) and M0 = f.f^T (Gram, octet-cooperative). Hops 1-2 are
// 5x5 register GEMMs: C <- A*C*Ah^T, M <- A*M*A^T, sqf = diag(M).
// One barrier total; all other LDS deps octet-local (same wave).
__global__ __launch_bounds__(256) void kc_main(
    const float* __restrict__ adjs,
    const float* __restrict__ feature,
    const int* __restrict__ idxs,
    const float* __restrict__ ws,
    float* __restrict__ out,
    int B, int N)
{
  __shared__ float fh[FH0_SZ];           // 10880 B (hop-0 only)
  __shared__ float nsqh[KSTEP*NF*SS];    // 480 B
  __shared__ float fS[BT][SS][FH_PAD];   // 43520 B
  __shared__ float Msh[BT][17];          // 2176 B  -> ~55.7 KB, 2 blocks/CU

  const int t    = threadIdx.x;
  const int lane = t & 63;
  const int wv   = t >> 6;
  const int b_i  = t >> 3;     // octet = one b
  const int f_   = t & 7;      // filter owner
  const int bg   = blockIdx.x * BT + b_i;
  const bool valid = bg < B;

  // async stage hop-0 fh (2720 floats) in 1KB chunks, waves interleaved
  for (int c = wv; c < 11; c += 4) {
    if (c < 10 || lane < 40)
      __builtin_amdgcn_global_load_lds(
          (const __attribute__((address_space(1))) void*)(ws + c*256 + lane*4),
          (__attribute__((address_space(3))) void*)(fh + c*256), 16, 0, 0);
  }
  if (t < KSTEP*NF*SS) nsqh[t] = ws[NSQ_OFF + t];

  // A into registers early (octet-broadcast; block's region is ~3.2KB)
  float A_[SS*SS];
  #pragma unroll
  for (int k = 0; k < SS*SS; ++k)
    A_[k] = valid ? adjs[(size_t)bg*(SS*SS) + k] : 0.0f;

  // gather: thread fetches d-columns [8f_, 8f_+8) of its b into fS
  #pragma unroll
  for (int m = 0; m < SS; ++m) {
    int id = valid ? idxs[bg*SS + m] : -1;
    #pragma unroll
    for (int h2 = 0; h2 < 2; ++h2) {
      float4 v = make_float4(0.f, 0.f, 0.f, 0.f);
      if ((unsigned)id < (unsigned)N)
        v = reinterpret_cast<const float4*>(feature)[(size_t)id*16 + f_*2 + h2];
      *reinterpret_cast<float4*>(&fS[b_i][m][f_*8 + h2*4]) = v;
    }
  }

  __syncthreads();  // drains async fh; fS octet-local

  // ---- hop-0 cross: C = G = f . fh^T  (the only d=64 contraction) ----
  float C[SS][SS];
  #pragma unroll
  for (int m = 0; m < SS; ++m)
    #pragma unroll
    for (int s = 0; s < SS; ++s) C[m][s] = 0.0f;

  const float* fhh = &fh[f_*FSTR];
  #pragma unroll
  for (int d4 = 0; d4 < 16; ++d4) {
    float4 fv[SS], hv[SS];
    #pragma unroll
    for (int m = 0; m < SS; ++m)
      fv[m] = *reinterpret_cast<const float4*>(&fS[b_i][m][d4*4]);
    #pragma unroll
    for (int s = 0; s < SS; ++s)
      hv[s] = *reinterpret_cast<const float4*>(&fhh[s*FH_PAD + d4*4]);
    #pragma unroll
    for (int m = 0; m < SS; ++m)
      #pragma unroll
      for (int s = 0; s < SS; ++s) {
        C[m][s] = fmaf(fv[m].x, hv[s].x, C[m][s]);
        C[m][s] = fmaf(fv[m].y, hv[s].y, C[m][s]);
        C[m][s] = fmaf(fv[m].z, hv[s].z, C[m][s]);
        C[m][s] = fmaf(fv[m].w, hv[s].w, C[m][s]);
      }
  }

  // ---- M0 Gram, octet-cooperative: lane f_ computes entries f_ and f_+8 ----
  int i0, j0, i1, j1;
  tri_ij(f_, i0, j0);
  const int e1 = f_ + 8;
  tri_ij(e1 > 14 ? 14 : e1, i1, j1);
  {
    const float* fb = &fS[b_i][0][0];
    const float* r0 = fb + i0*FH_PAD;
    const float* r1 = fb + j0*FH_PAD;
    const float* r2 = fb + i1*FH_PAD;
    const float* r3 = fb + j1*FH_PAD;
    float m0 = 0.0f, m1 = 0.0f;
    #pragma unroll
    for (int d4 = 0; d4 < 16; ++d4) {
      float4 va = *reinterpret_cast<const float4*>(&r0[d4*4]);
      float4 vb = *reinterpret_cast<const float4*>(&r1[d4*4]);
      float4 vc = *reinterpret_cast<const float4*>(&r2[d4*4]);
      float4 vd = *reinterpret_cast<const float4*>(&r3[d4*4]);
      m0 = fmaf(va.x, vb.x, m0); m0 = fmaf(va.y, vb.y, m0);
      m0 = fmaf(va.z, vb.z, m0); m0 = fmaf(va.w, vb.w, m0);
      m1 = fmaf(vc.x, vd.x, m1); m1 = fmaf(vc.y, vd.y, m1);
      m1 = fmaf(vc.z, vd.z, m1); m1 = fmaf(vc.w, vd.w, m1);
    }
    Msh[b_i][f_] = m0;
    if (e1 < 15) Msh[b_i][e1] = m1;
  }
  // octet-local write->read, same wave: no barrier
  float M[15];
  #pragma unroll
  for (int e = 0; e < 15; ++e) M[e] = Msh[b_i][e];

  float total[SS][SS];

  // ---- hop 0 accumulate ----
  {
    float nh[SS];
    #pragma unroll
    for (int s = 0; s < SS; ++s) nh[s] = nsqh[0*NF*SS + f_*SS + s];
    #pragma unroll
    for (int m = 0; m < SS; ++m) {
      float sm = CS * M[midx(m, m)];
      #pragma unroll
      for (int s = 0; s < SS; ++s)
        total[m][s] = fexp2(fmaf(CC, C[m][s], nh[s] - sm));
    }
  }

  // Ah now (L2-hot, 800B chip-wide)
  float Ah_[SS*SS];
  #pragma unroll
  for (int k = 0; k < SS*SS; ++k)
    Ah_[k] = ws[AH_OFF + f_*SS*SS + k];

  // ---- hops 1..2: 5x5 register updates ----
  #pragma unroll
  for (int hop = 1; hop < KSTEP; ++hop) {
    // C <- A * C * Ah^T
    float T[SS][SS];
    #pragma unroll
    for (int i = 0; i < SS; ++i)
      #pragma unroll
      for (int k = 0; k < SS; ++k) {
        float acc = 0.0f;
        #pragma unroll
        for (int j = 0; j < SS; ++j) acc = fmaf(A_[i*SS+j], C[j][k], acc);
        T[i][k] = acc;
      }
    #pragma unroll
    for (int i = 0; i < SS; ++i)
      #pragma unroll
      for (int s = 0; s < SS; ++s) {
        float acc = 0.0f;
        #pragma unroll
        for (int k = 0; k < SS; ++k) acc = fmaf(T[i][k], Ah_[s*SS+k], acc);
        C[i][s] = acc;
      }

    // TM = A * M  (M symmetric, 15 entries)
    float TM[SS][SS];
    #pragma unroll
    for (int i = 0; i < SS; ++i)
      #pragma unroll
      for (int l = 0; l < SS; ++l) {
        float acc = 0.0f;
        #pragma unroll
        for (int k = 0; k < SS; ++k) acc = fmaf(A_[i*SS+k], M[midx(k, l)], acc);
        TM[i][l] = acc;
      }

    float sqf2[SS];
    if (hop + 1 < KSTEP) {
      // full M <- TM * A^T (needed for next hop); uses only TM,A -> in place
      #pragma unroll
      for (int i = 0; i < SS; ++i)
        #pragma unroll
        for (int j = i; j < SS; ++j) {
          float acc = 0.0f;
          #pragma unroll
          for (int l = 0; l < SS; ++l) acc = fmaf(TM[i][l], A_[j*SS+l], acc);
          M[midx(i, j)] = acc;
        }
      #pragma unroll
      for (int m = 0; m < SS; ++m) sqf2[m] = CS * M[midx(m, m)];
    } else {
      // last hop: diag only
      #pragma unroll
      for (int m = 0; m < SS; ++m) {
        float acc = 0.0f;
        #pragma unroll
        for (int l = 0; l < SS; ++l) acc = fmaf(TM[m][l], A_[m*SS+l], acc);
        sqf2[m] = CS * acc;
      }
    }

    float nh[SS];
    #pragma unroll
    for (int s = 0; s < SS; ++s) nh[s] = nsqh[hop*NF*SS + f_*SS + s];
    #pragma unroll
    for (int m = 0; m < SS; ++m)
      #pragma unroll
      for (int s = 0; s < SS; ++s)
        total[m][s] += fexp2(fmaf(CC, C[m][s], nh[s] - sqf2[m]));
  }

  // greedy matching: row 0 -> col 0; rows 1..4 argmax over untaken cols
  float res = total[0][0];
  int taken = 1;
  #pragma unroll
  for (int r = 1; r < SS; ++r) {
    float best = -2.0f; int bi = 0;
    #pragma unroll
    for (int s = 0; s < SS; ++s) {
      float sc = ((taken >> s) & 1) ? -1.0f : total[r][s];
      if (sc > best) { best = sc; bi = s; }
    }
    res += best;
    taken |= (1 << bi);
  }
  if (valid) out[(size_t)bg*NF + f_] = res;
}

extern "C" void kernel_launch(void* const* d_in, const int* in_sizes, int n_in,
                              void* d_out, int out_size, void* d_ws, size_t ws_size,
                              hipStream_t stream) {
  const float* adjs            = (const float*)d_in[0];
  const float* feature         = (const float*)d_in[1];
  const int*   idxs            = (const int*)d_in[2];
  const float* adjs_hidden     = (const float*)d_in[3];
  const float* features_hidden = (const float*)d_in[4];
  float* out = (float*)d_out;
  float* ws  = (float*)d_ws;

  const int B = in_sizes[0] / (SS*SS);
  const int N = in_sizes[1] / DIN;

  hipLaunchKernelGGL(hidden_prep, dim3(1), dim3(256), 0, stream,
                     adjs_hidden, features_hidden, ws);
  const int nblk = (B + BT - 1) / BT;
  hipLaunchKernelGGL(kc_main, dim3(nblk), dim3(256), 0, stream,
                     adjs, feature, idxs, ws, out, B, N);
}

// Round 9
// 373.008 us; speedup vs baseline: 1.0420x; 1.0420x over previous
//
#include <hip/hip_runtime.h>
#include <math.h>

#define NF 8
#define SS 5
#define DIN 64
#define KSTEP 3
#define BT 32
#define FH_PAD 68              // padded row (16B-aligned, bank spread)
#define FSTR (SS*FH_PAD)       // 340 (%32 = 20 -> 8 distinct start banks)
#define FH0_SZ (NF*FSTR)       // 2720 floats: hop-0 fh, padded
#define NSQ_OFF FH0_SZ         // ws: nsqh [3][8][5]
#define AH_OFF  (FH0_SZ + KSTEP*NF*SS)   // ws: Ah [8][5][5]

// exp(-(sqf+sqh-2cr)/3.2) = 2^(CC*cr - CS*sqf - CS*sqh)
#define CS 0.45084219902780109f
#define CC 0.90168439805560218f

__device__ __forceinline__ float fexp2(float x) {
#if __has_builtin(__builtin_amdgcn_exp2f)
  return __builtin_amdgcn_exp2f(x);
#else
  return exp2f(x);
#endif
}

// symmetric 5x5 index (i<=j): base i*(9-i)/2 + j ; folds at compile time
__device__ __forceinline__ constexpr int midx(int i, int j) {
  return (i <= j) ? (i*(9-i))/2 + j : (j*(9-j))/2 + i;
}

// e in [0,15) -> (i,j) upper-triangle entry
__device__ __forceinline__ void tri_ij(int e, int& i, int& j) {
  int i_ = (e >= 5) + (e >= 9) + (e >= 12) + (e >= 14);
  int off = (i_ == 0) ? 0 : (i_ == 1) ? 4 : (i_ == 2) ? 7 : (i_ == 3) ? 9 : 10;
  i = i_; j = e - off;
}

__global__ __launch_bounds__(256) void hidden_prep(
    const float* __restrict__ adjs_hidden,
    const float* __restrict__ features_hidden,
    float* __restrict__ ws)
{
  __shared__ float Ah[NF][SS][SS];
  __shared__ float buf[2][NF][SS][DIN];
  const int t = threadIdx.x;

  if (t < NF*SS*SS) ((float*)Ah)[t] = 0.0f;
  for (int i = t; i < NF*SS*DIN; i += 256) ((float*)buf[0])[i] = features_hidden[i];
  __syncthreads();
  if (t < NF*10) {
    const int iu0[10] = {0,0,0,0,1,1,1,2,2,3};
    const int iu1[10] = {1,2,3,4,2,3,4,3,4,4};
    int f = t / 10, k = t % 10;
    float sg = 1.0f / (1.0f + expf(-adjs_hidden[t]));
    Ah[f][iu0[k]][iu1[k]] = sg;
    Ah[f][iu1[k]][iu0[k]] = sg;
  }
  __syncthreads();

  // export Ah for the main kernel
  if (t < NF*SS*SS) ws[AH_OFF + t] = ((float*)Ah)[t];

  int cur = 0;
  for (int h = 0; h < KSTEP; ++h) {
    // hop-0 fh only (padded layout for LDS staging)
    if (h == 0) {
      for (int i = t; i < NF*SS*DIN; i += 256) {
        int f = i / (SS*DIN), s = (i / DIN) % SS, d = i % DIN;
        ws[f*FSTR + s*FH_PAD + d] = buf[cur][f][s][d];
      }
    }
    // negated, pre-scaled sq_h (all hops)
    if (t < NF*SS) {
      float acc = 0.0f;
      int f = t / SS, s = t % SS;
      for (int d = 0; d < DIN; ++d) { float v = buf[cur][f][s][d]; acc = fmaf(v, v, acc); }
      ws[NSQ_OFF + h*NF*SS + t] = -acc * CS;
    }
    if (h + 1 < KSTEP) {
      __syncthreads();
      for (int i = t; i < NF*SS*DIN; i += 256) {
        int f = i / (SS*DIN), s = (i / DIN) % SS, d = i % DIN;
        float acc = 0.0f;
        for (int j = 0; j < SS; ++j) acc = fmaf(Ah[f][s][j], buf[cur][f][j][d], acc);
        buf[cur^1][f][s][d] = acc;
      }
      __syncthreads();
      cur ^= 1;
    }
  }
}

// Linearity restructure, register-pressure-fixed:
//   hop0: C = f.fh^T (only d=64 contraction), M0 = Gram(f) via LDS pointers
//   hops 1-2: C <- A*C*Ah^T, M <- A*M*A^T, sqf = diag(M)  (5x5 reg GEMMs)
// A in registers but loaded AFTER hop0 (sched_barrier fence); Ah read from
// LDS scalar-wise (value reused 5x per load). One barrier total.
__global__ __launch_bounds__(256) void kc_main(
    const float* __restrict__ adjs,
    const float* __restrict__ feature,
    const int* __restrict__ idxs,
    const float* __restrict__ ws,
    float* __restrict__ out,
    int B, int N)
{
  __shared__ float fh[FH0_SZ];           // 10880 B (hop-0 only)
  __shared__ float nsqh[KSTEP*NF*SS];    // 480 B
  __shared__ float ahS[NF*SS*SS];        // 800 B
  __shared__ float fS[BT][SS][FH_PAD];   // 43520 B
  __shared__ float Msh[BT][17];          // 2176 B  -> ~57.9 KB, 2 blocks/CU

  const int t    = threadIdx.x;
  const int lane = t & 63;
  const int wv   = t >> 6;
  const int b_i  = t >> 3;     // octet = one b
  const int f_   = t & 7;      // filter owner
  const int bg   = blockIdx.x * BT + b_i;
  const bool valid = bg < B;

  // async stage hop-0 fh (2720 floats) in 1KB chunks, waves interleaved
  for (int c = wv; c < 11; c += 4) {
    if (c < 10 || lane < 40)
      __builtin_amdgcn_global_load_lds(
          (const __attribute__((address_space(1))) void*)(ws + c*256 + lane*4),
          (__attribute__((address_space(3))) void*)(fh + c*256), 16, 0, 0);
  }
  if (t < KSTEP*NF*SS) nsqh[t] = ws[NSQ_OFF + t];
  if (t < NF*SS*SS)    ahS[t]  = ws[AH_OFF + t];

  // gather: thread fetches d-columns [8f_, 8f_+8) of its b into fS
  #pragma unroll
  for (int m = 0; m < SS; ++m) {
    int id = valid ? idxs[bg*SS + m] : -1;
    #pragma unroll
    for (int h2 = 0; h2 < 2; ++h2) {
      float4 v = make_float4(0.f, 0.f, 0.f, 0.f);
      if ((unsigned)id < (unsigned)N)
        v = reinterpret_cast<const float4*>(feature)[(size_t)id*16 + f_*2 + h2];
      *reinterpret_cast<float4*>(&fS[b_i][m][f_*8 + h2*4]) = v;
    }
  }

  __syncthreads();  // drains async fh; ahS/nsqh visible; fS octet-local

  // ---- hop-0 cross: C = f . fh^T  (the only d=64 contraction) ----
  float C[SS][SS];
  #pragma unroll
  for (int m = 0; m < SS; ++m)
    #pragma unroll
    for (int s = 0; s < SS; ++s) C[m][s] = 0.0f;

  const float* fhh = &fh[f_*FSTR];
  #pragma unroll
  for (int d4 = 0; d4 < 16; ++d4) {
    float4 fv[SS], hv[SS];
    #pragma unroll
    for (int m = 0; m < SS; ++m)
      fv[m] = *reinterpret_cast<const float4*>(&fS[b_i][m][d4*4]);
    #pragma unroll
    for (int s = 0; s < SS; ++s)
      hv[s] = *reinterpret_cast<const float4*>(&fhh[s*FH_PAD + d4*4]);
    #pragma unroll
    for (int m = 0; m < SS; ++m)
      #pragma unroll
      for (int s = 0; s < SS; ++s) {
        C[m][s] = fmaf(fv[m].x, hv[s].x, C[m][s]);
        C[m][s] = fmaf(fv[m].y, hv[s].y, C[m][s]);
        C[m][s] = fmaf(fv[m].z, hv[s].z, C[m][s]);
        C[m][s] = fmaf(fv[m].w, hv[s].w, C[m][s]);
      }
  }

  // ---- M0 Gram, octet-cooperative: lane f_ computes entries f_ and f_+8 ----
  {
    int i0, j0, i1, j1;
    tri_ij(f_, i0, j0);
    const int e1 = f_ + 8;
    tri_ij(e1 > 14 ? 14 : e1, i1, j1);
    const float* fb = &fS[b_i][0][0];
    const float* r0 = fb + i0*FH_PAD;
    const float* r1 = fb + j0*FH_PAD;
    const float* r2 = fb + i1*FH_PAD;
    const float* r3 = fb + j1*FH_PAD;
    float m0 = 0.0f, m1 = 0.0f;
    #pragma unroll
    for (int d4 = 0; d4 < 16; ++d4) {
      float4 va = *reinterpret_cast<const float4*>(&r0[d4*4]);
      float4 vb = *reinterpret_cast<const float4*>(&r1[d4*4]);
      float4 vc = *reinterpret_cast<const float4*>(&r2[d4*4]);
      float4 vd = *reinterpret_cast<const float4*>(&r3[d4*4]);
      m0 = fmaf(va.x, vb.x, m0); m0 = fmaf(va.y, vb.y, m0);
      m0 = fmaf(va.z, vb.z, m0); m0 = fmaf(va.w, vb.w, m0);
      m1 = fmaf(vc.x, vd.x, m1); m1 = fmaf(vc.y, vd.y, m1);
      m1 = fmaf(vc.z, vd.z, m1); m1 = fmaf(vc.w, vd.w, m1);
    }
    Msh[b_i][f_] = m0;
    if (e1 < 15) Msh[b_i][e1] = m1;
  }
  // octet-local write->read, same wave: no barrier
  float M[15];
  #pragma unroll
  for (int e = 0; e < 15; ++e) M[e] = Msh[b_i][e];

  float total[SS][SS];

  // ---- hop 0 accumulate ----
  {
    float nh[SS];
    #pragma unroll
    for (int s = 0; s < SS; ++s) nh[s] = nsqh[0*NF*SS + f_*SS + s];
    #pragma unroll
    for (int m = 0; m < SS; ++m) {
      float sm = CS * M[midx(m, m)];
      #pragma unroll
      for (int s = 0; s < SS; ++s)
        total[m][s] = fexp2(fmaf(CC, C[m][s], nh[s] - sm));
    }
  }

  // fence: keep the A loads OUT of the hop-0 region (register pressure)
  __builtin_amdgcn_sched_barrier(0);

  // A into registers now (octet-broadcast, L2-hot)
  float A_[SS*SS];
  #pragma unroll
  for (int k = 0; k < SS*SS; ++k)
    A_[k] = valid ? adjs[(size_t)bg*(SS*SS) + k] : 0.0f;

  const float* ahf = &ahS[f_*SS*SS];

  // ---- hops 1..2: 5x5 register updates ----
  #pragma unroll
  for (int hop = 1; hop < KSTEP; ++hop) {
    // T = A * C
    float T[SS][SS];
    #pragma unroll
    for (int i = 0; i < SS; ++i)
      #pragma unroll
      for (int k = 0; k < SS; ++k) {
        float acc = 0.0f;
        #pragma unroll
        for (int j = 0; j < SS; ++j) acc = fmaf(A_[i*SS+j], C[j][k], acc);
        T[i][k] = acc;
      }
    // C = T * Ah^T  (Ah from LDS, each scalar reused 5x)
    #pragma unroll
    for (int s = 0; s < SS; ++s) {
      #pragma unroll
      for (int i = 0; i < SS; ++i) C[i][s] = 0.0f;
      #pragma unroll
      for (int k = 0; k < SS; ++k) {
        float ah = ahf[s*SS + k];
        #pragma unroll
        for (int i = 0; i < SS; ++i) C[i][s] = fmaf(T[i][k], ah, C[i][s]);
      }
    }

    // TM = A * M  (M symmetric, 15 entries)
    float TM[SS][SS];
    #pragma unroll
    for (int i = 0; i < SS; ++i)
      #pragma unroll
      for (int l = 0; l < SS; ++l) {
        float acc = 0.0f;
        #pragma unroll
        for (int k = 0; k < SS; ++k) acc = fmaf(A_[i*SS+k], M[midx(k, l)], acc);
        TM[i][l] = acc;
      }

    float sqf2[SS];
    if (hop + 1 < KSTEP) {
      // full M <- TM * A^T (needed for next hop)
      #pragma unroll
      for (int i = 0; i < SS; ++i)
        #pragma unroll
        for (int j = i; j < SS; ++j) {
          float acc = 0.0f;
          #pragma unroll
          for (int l = 0; l < SS; ++l) acc = fmaf(TM[i][l], A_[j*SS+l], acc);
          M[midx(i, j)] = acc;
        }
      #pragma unroll
      for (int m = 0; m < SS; ++m) sqf2[m] = CS * M[midx(m, m)];
    } else {
      // last hop: diag only
      #pragma unroll
      for (int m = 0; m < SS; ++m) {
        float acc = 0.0f;
        #pragma unroll
        for (int l = 0; l < SS; ++l) acc = fmaf(TM[m][l], A_[m*SS+l], acc);
        sqf2[m] = CS * acc;
      }
    }

    float nh[SS];
    #pragma unroll
    for (int s = 0; s < SS; ++s) nh[s] = nsqh[hop*NF*SS + f_*SS + s];
    #pragma unroll
    for (int m = 0; m < SS; ++m)
      #pragma unroll
      for (int s = 0; s < SS; ++s)
        total[m][s] += fexp2(fmaf(CC, C[m][s], nh[s] - sqf2[m]));
  }

  // greedy matching: row 0 -> col 0; rows 1..4 argmax over untaken cols
  float res = total[0][0];
  int taken = 1;
  #pragma unroll
  for (int r = 1; r < SS; ++r) {
    float best = -2.0f; int bi = 0;
    #pragma unroll
    for (int s = 0; s < SS; ++s) {
      float sc = ((taken >> s) & 1) ? -1.0f : total[r][s];
      if (sc > best) { best = sc; bi = s; }
    }
    res += best;
    taken |= (1 << bi);
  }
  if (valid) out[(size_t)bg*NF + f_] = res;
}

extern "C" void kernel_launch(void* const* d_in, const int* in_sizes, int n_in,
                              void* d_out, int out_size, void* d_ws, size_t ws_size,
                              hipStream_t stream) {
  const float* adjs            = (const float*)d_in[0];
  const float* feature         = (const float*)d_in[1];
  const int*   idxs            = (const int*)d_in[2];
  const float* adjs_hidden     = (const float*)d_in[3];
  const float* features_hidden = (const float*)d_in[4];
  float* out = (float*)d_out;
  float* ws  = (float*)d_ws;

  const int B = in_sizes[0] / (SS*SS);
  const int N = in_sizes[1] / DIN;

  hipLaunchKernelGGL(hidden_prep, dim3(1), dim3(256), 0, stream,
                     adjs_hidden, features_hidden, ws);
  const int nblk = (B + BT - 1) / BT;
  hipLaunchKernelGGL(kc_main, dim3(nblk), dim3(256), 0, stream,
                     adjs, feature, idxs, ws, out, B, N);
}